// Round 10
// baseline (48.449 us; speedup 1.0000x reference)
//
#include <hip/hip_runtime.h>

#define HOP     256
#define WD      32
#define NFRM    4096
#define TLEN    1048832        // FRAMELEN + HOP*(NFRM-1)
#define LROW    786688         // 448 + 4095*192
#define XSTR    484            // x floats per frame (121 quads; 484 % 32 == 4)
#define DSTR    420            // g floats per chain (105 quads; 420 % 32 == 4)
#define XQn     121
#define DQn     105
#define XTOT    (4*XSTR + 16)  // 1952
#define GTOT    (8*DSTR + 8)   // 3368

// one butterfly level: v += dpp<CTRL>(v); GCNDPPCombine folds to v_add_f32_dpp
template<int C>
__device__ __forceinline__ float dpa(float v) {
    return v + __int_as_float(
        __builtin_amdgcn_update_dpp(0, __float_as_int(v), C, 0xF, 0xF, true));
}

#define CL(v) __builtin_amdgcn_fmed3f((v), -65535.0f, 65535.0f)

// One LMS step for BOTH independent chain-sets, interleaved line-by-line so
// set B's instructions fill set A's DPP-hazard/latency slots (and vice versa).
#define STEP2(AXa,AXb,AXc,AXd,AGV, BXa,BXb,BXc,BXd,BGV, IND) do {        \
    float ap0 = aw0 * (AXa);             float bp0 = bw0 * (BXa);        \
    float ap1 = aw2 * (AXc);             float bp1 = bw2 * (BXc);        \
    ap0 = fmaf(aw1, (AXb), ap0);         bp0 = fmaf(bw1, (BXb), bp0);    \
    ap1 = fmaf(aw3, (AXd), ap1);         bp1 = fmaf(bw3, (BXd), bp1);    \
    float ap = ap0 + ap1;                float bp = bp0 + bp1;           \
    ap = dpa<0xB1>(ap);                  bp = dpa<0xB1>(bp);             \
    ap = dpa<0x4E>(ap);                  bp = dpa<0x4E>(bp);             \
    ap = dpa<0x141>(ap);                 bp = dpa<0x141>(bp);            \
    ap = dpa<0x140>(ap);                 bp = dpa<0x140>(bp);            \
    aso = fmaf((IND), ap, aso);          bso = fmaf((IND), bp, bso);     \
    float agm = fmaf(-0.05f, ap, (AGV)); float bgm = fmaf(-0.05f, bp, (BGV)); \
    aw0 = CL(fmaf(agm, (AXa), aw0));     bw0 = CL(fmaf(bgm, (BXa), bw0)); \
    aw1 = CL(fmaf(agm, (AXb), aw1));     bw1 = CL(fmaf(bgm, (BXb), bw1)); \
    aw2 = CL(fmaf(agm, (AXc), aw2));     bw2 = CL(fmaf(bgm, (BXc), bw2)); \
    aw3 = CL(fmaf(agm, (AXd), aw3));     bw3 = CL(fmaf(bgm, (BXd), bw3)); \
} while (0)

#define GROUP2(AQA,AQB,AGQ, BQA,BQB,BGQ, Ia,Ib,Ic,Id) do {               \
    STEP2(AQA.x,AQA.y,AQA.z,AQA.w, AGQ.x,                                \
          BQA.x,BQA.y,BQA.z,BQA.w, BGQ.x, Ia);                           \
    STEP2(AQA.y,AQA.z,AQA.w,AQB.x, AGQ.y,                                \
          BQA.y,BQA.z,BQA.w,BQB.x, BGQ.y, Ib);                           \
    STEP2(AQA.z,AQA.w,AQB.x,AQB.y, AGQ.z,                                \
          BQA.z,BQA.w,BQB.x,BQB.y, BGQ.z, Ic);                           \
    STEP2(AQA.w,AQB.x,AQB.y,AQB.z, AGQ.w,                                \
          BQA.w,BQB.x,BQB.y,BQB.z, BGQ.w, Id);                           \
} while (0)

// block = 64 threads = 1 wave = 2 interleaved sets x 4 chains (L=16)
// = 4 frames x 2 batches. 1024 blocks -> 1 wave/SIMD, stall-hiding by ILP.
__global__ void __launch_bounds__(64, 1)
lms_kernel(const float* __restrict__ dmat, const float* __restrict__ xvec,
           float* __restrict__ out)
{
    __shared__ __align__(16) float lx[XTOT];
    __shared__ __align__(16) float lg[GTOT];   // 0.05 * d, per chain

    const int tid = threadIdx.x;
    const int f0  = blockIdx.x * 4;

    // ---- stage: 484 x-quads + 840 g-quads (0.05*d) ----
    for (int i = tid; i < 484 + 840; i += 64) {
        if (i < 484) {
            int fr = i / XQn, k = i - fr * XQn;
            ((float4*)lx)[i] =
                *(const float4*)(xvec + (size_t)(f0 + fr) * HOP + 4 * k);
        } else {
            int j   = i - 484;
            int idx = j / DQn, k = j - idx * DQn;   // idx = b*4 + r
            int b = idx >> 2, r = idx & 3;
            float4 v = *(const float4*)(dmat + (size_t)b * TLEN
                                        + (size_t)(f0 + r) * HOP + WD + 4 * k);
            float4 g2;
            g2.x = 0.05f * v.x; g2.y = 0.05f * v.y;
            g2.z = 0.05f * v.z; g2.w = 0.05f * v.w;
            ((float4*)lg)[j] = g2;
        }
    }
    __syncthreads();

    const int row  = tid >> 4;             // 0..3
    const int col  = tid & 15;             // taps 4*col .. 4*col+3
    const int flA  = row >> 1;             // set A local frame 0..1
    const int b    = row & 1;              // batch
    const int fA   = f0 + flA;             // set A global frame
    const int fB   = fA + 2;               // set B global frame (never 0)
    const bool earlyA = (fA == 0);
    const int ciA  = b * 4 + flA;          // set A chain slot
    const int ciB  = ciA + 2;              // set B chain slot

    const float4* __restrict__ xqA = (const float4*)(lx + flA * XSTR + 4 * col);
    const float4* __restrict__ xqB = (const float4*)(lx + (flA + 2) * XSTR + 4 * col);
    const float4* __restrict__ gqA = (const float4*)(lg + ciA * DSTR);
    const float4* __restrict__ gqB = (const float4*)(lg + ciB * DSTR);
    const float*  __restrict__ lgsA = lg + ciA * DSTR;
    const float*  __restrict__ lgsB = lg + ciB * DSTR;

    float* odA = out + (size_t)b * LROW + 32 + (size_t)192 * fA;
    float* oeA = odA + 2 * (size_t)LROW;
    float* odB = out + (size_t)b * LROW + 32 + (size_t)192 * fB;
    float* oeB = odB + 2 * (size_t)LROW;

    // leading 32 zeros of the 4 output rows
    if (blockIdx.x == 0) {
        for (int z = tid; z < 128; z += 64)
            out[(size_t)(z >> 5) * LROW + (z & 31)] = 0.0f;
    }

    // per-lane step indicators (statically indexed -> registers)
    const float i0  = (col ==  0) ? 1.f : 0.f, i1  = (col ==  1) ? 1.f : 0.f;
    const float i2  = (col ==  2) ? 1.f : 0.f, i3  = (col ==  3) ? 1.f : 0.f;
    const float i4  = (col ==  4) ? 1.f : 0.f, i5  = (col ==  5) ? 1.f : 0.f;
    const float i6  = (col ==  6) ? 1.f : 0.f, i7  = (col ==  7) ? 1.f : 0.f;
    const float i8  = (col ==  8) ? 1.f : 0.f, i9  = (col ==  9) ? 1.f : 0.f;
    const float i10 = (col == 10) ? 1.f : 0.f, i11 = (col == 11) ? 1.f : 0.f;
    const float i12 = (col == 12) ? 1.f : 0.f, i13 = (col == 13) ? 1.f : 0.f;
    const float i14 = (col == 14) ? 1.f : 0.f, i15 = (col == 15) ? 1.f : 0.f;

    float aw0=0.f, aw1=0.f, aw2=0.f, aw3=0.f;
    float bw0=0.f, bw1=0.f, bw2=0.f, bw3=0.f;

    // prologue: 2-group lead, both sets
    float4 aX0 = xqA[0], aX1 = xqA[1], aX2 = xqA[2];
    float4 bX0 = xqB[0], bX1 = xqB[1], bX2 = xqB[2];
    float4 aG0 = gqA[0], aG1 = gqA[1];
    float4 bG0 = gqB[0], bG1 = gqB[1];

    for (int j = 0; j < 26; ++j) {
        const int g = 4 * j;
        float aso = 0.f, bso = 0.f;
        float agvs = lgsA[16 * j + col];
        float bgvs = lgsB[16 * j + col];

        float4 aX3 = xqA[g+3];  float4 aG2 = gqA[g+2];
        float4 bX3 = xqB[g+3];  float4 bG2 = gqB[g+2];
        GROUP2(aX0, aX1, aG0,  bX0, bX1, bG0,  i0,  i1,  i2,  i3);

        aX0 = xqA[g+4];         float4 aG3 = gqA[g+3];
        bX0 = xqB[g+4];         float4 bG3 = gqB[g+3];
        GROUP2(aX1, aX2, aG1,  bX1, bX2, bG1,  i4,  i5,  i6,  i7);

        aX1 = xqA[g+5];         aG0 = gqA[g+4];
        bX1 = xqB[g+5];         bG0 = gqB[g+4];
        GROUP2(aX2, aX3, aG2,  bX2, bX3, bG2,  i8,  i9,  i10, i11);

        aX2 = xqA[g+6];         aG1 = gqA[g+5];
        bX2 = xqB[g+6];         bG1 = gqB[g+5];
        GROUP2(aX3, aX0, aG3,  bX3, bX0, bG3,  i12, i13, i14, i15);

        if (j >= 14 || earlyA) {
            float agms = fmaf(-0.05f, aso, agvs);  // == in-loop gm bitwise
            odA[16 * j + col] = aso;               // d_est
            oeA[16 * j + col] = 20.0f * agms;      // e = 20 * (0.05*e)
        }
        if (j >= 14) {
            float bgms = fmaf(-0.05f, bso, bgvs);
            odB[16 * j + col] = bso;
            oeB[16 * j + col] = 20.0f * bgms;
        }
    }
}

extern "C" void kernel_launch(void* const* d_in, const int* in_sizes, int n_in,
                              void* d_out, int out_size, void* d_ws, size_t ws_size,
                              hipStream_t stream) {
    const float* dmat = (const float*)d_in[0];   // (2, TLEN)
    const float* xvec = (const float*)d_in[1];   // (TLEN,)
    float* out = (float*)d_out;                  // [d_est(2,LROW), e(2,LROW)]

    hipLaunchKernelGGL(lms_kernel, dim3(NFRM / 4), dim3(64), 0, stream,
                       dmat, xvec, out);
}

// Round 11
// 36.766 us; speedup vs baseline: 1.3178x; 1.3178x over previous
//
#include <hip/hip_runtime.h>

#define HOP     256
#define WD      32
#define NFRM    4096
#define TLEN    1048832        // FRAMELEN + HOP*(NFRM-1)
#define LROW    786688         // 448 + 4095*192
#define XSTR    484            // x floats per frame (121 quads; 484 % 32 == 4)
#define DSTR    420            // g floats per chain (105 quads; 420 % 32 == 4)
#define XQn     121
#define DQn     105
#define XTOT    (2*XSTR + 16)  // 984  (+guard for dead prefetch overrun)
#define GTOT    (4*DSTR + 8)   // 1688

// 16-lane xor-butterfly sum within each row of 16; result in all 16 lanes.
// Hand-written minimal-hazard form: 4 x v_add_f32_dpp with exactly the
// required 2 wait-states (s_nop 1) per VALU->DPP dependence. Arithmetic
// and operand order identical to the previous builtin version.
__device__ __forceinline__ float red16(float v) {
    float r = v;
    asm volatile(
        "s_nop 1\n\t"                                                      // entry hazard: r written by VALU just before
        "v_add_f32_dpp %0, %0, %0 quad_perm:[1,0,3,2] row_mask:0xf bank_mask:0xf\n\t"
        "s_nop 1\n\t"
        "v_add_f32_dpp %0, %0, %0 quad_perm:[2,3,0,1] row_mask:0xf bank_mask:0xf\n\t"
        "s_nop 1\n\t"
        "v_add_f32_dpp %0, %0, %0 row_half_mirror row_mask:0xf bank_mask:0xf\n\t"
        "s_nop 1\n\t"
        "v_add_f32_dpp %0, %0, %0 row_mirror row_mask:0xf bank_mask:0xf\n\t"
        : "+v"(r));
    return r;
}

#define CL(v) __builtin_amdgcn_fmed3f((v), -65535.0f, 65535.0f)

// One LMS step. GV = 0.05*d (pre-scaled). gm = fmaf(-0.05, s, GV) = 0.05*e.
// Capture: so += IND * s  (IND is 1.0 in exactly one lane's step per 16).
#define STEP1(Xa,Xb,Xc,Xd, GV, IND) do {                          \
    float p = w0 * (Xa);                                          \
    p = fmaf(w1, (Xb), p);                                        \
    p = fmaf(w2, (Xc), p);                                        \
    p = fmaf(w3, (Xd), p);                                        \
    float s  = red16(p);                                          \
    so = fmaf((IND), s, so);                                      \
    float gm = fmaf(-0.05f, s, (GV));                             \
    w0 = CL(fmaf(gm, (Xa), w0));                                  \
    w1 = CL(fmaf(gm, (Xb), w1));                                  \
    w2 = CL(fmaf(gm, (Xc), w2));                                  \
    w3 = CL(fmaf(gm, (Xd), w3));                                  \
} while (0)

#define GROUP4(QA, QB, GQ, Ia, Ib, Ic, Id) do {                   \
    STEP1(QA.x,QA.y,QA.z,QA.w, GQ.x, Ia);                         \
    STEP1(QA.y,QA.z,QA.w,QB.x, GQ.y, Ib);                         \
    STEP1(QA.z,QA.w,QB.x,QB.y, GQ.z, Ic);                         \
    STEP1(QA.w,QB.x,QB.y,QB.z, GQ.w, Id);                         \
} while (0)

// block = 64 threads = 1 wave = 4 chains (L=16) = 2 frames x 2 batches.
// 2048 blocks -> 2 waves/SIMD resident.
__global__ void __launch_bounds__(64, 2)
lms_kernel(const float* __restrict__ dmat, const float* __restrict__ xvec,
           float* __restrict__ out)
{
    __shared__ __align__(16) float lx[XTOT];
    __shared__ __align__(16) float lg[GTOT];   // 0.05 * d, per chain

    const int tid = threadIdx.x;
    const int f0  = blockIdx.x * 2;

    // ---- stage: 242 x-quads + 420 g-quads ----
    for (int i = tid; i < 242 + 420; i += 64) {
        if (i < 242) {
            int fr = (i >= XQn) ? 1 : 0;
            int k  = i - fr * XQn;
            ((float4*)lx)[i] =
                *(const float4*)(xvec + (size_t)(f0 + fr) * HOP + 4 * k);
        } else {
            int j   = i - 242;
            int idx = j / DQn, k = j - idx * DQn;   // idx = b*2 + r
            int b = idx >> 1, r = idx & 1;
            float4 v = *(const float4*)(dmat + (size_t)b * TLEN
                                        + (size_t)(f0 + r) * HOP + WD + 4 * k);
            float4 g2;
            g2.x = 0.05f * v.x; g2.y = 0.05f * v.y;
            g2.z = 0.05f * v.z; g2.w = 0.05f * v.w;
            ((float4*)lg)[j] = g2;
        }
    }
    __syncthreads();

    const int lane = tid & 63;
    const int row  = lane >> 4;            // 0..3
    const int col  = lane & 15;            // taps 4*col .. 4*col+3
    const int fl   = row >> 1;             // local frame 0..1
    const int b    = row & 1;              // batch
    const int f    = f0 + fl;              // global frame
    const bool early = (f == 0);
    const int ci   = b * 2 + fl;           // chain slot in lg

    const float4* __restrict__ xq  = (const float4*)(lx + fl * XSTR + 4 * col);
    const float4* __restrict__ gq  = (const float4*)(lg + ci * DSTR);
    const float*  __restrict__ lgs = lg + ci * DSTR;

    float* od = out + (size_t)b * LROW + 32 + (size_t)192 * f;
    float* oe = od + 2 * (size_t)LROW;

    // leading 32 zeros of the 4 output rows
    if (blockIdx.x == 0) {
        int pos = tid & 31;
        for (int r2 = tid >> 5; r2 < 4; r2 += 2)
            out[(size_t)r2 * LROW + pos] = 0.0f;
    }

    // per-lane step indicators (statically indexed -> registers)
    const float i0  = (col ==  0) ? 1.f : 0.f, i1  = (col ==  1) ? 1.f : 0.f;
    const float i2  = (col ==  2) ? 1.f : 0.f, i3  = (col ==  3) ? 1.f : 0.f;
    const float i4  = (col ==  4) ? 1.f : 0.f, i5  = (col ==  5) ? 1.f : 0.f;
    const float i6  = (col ==  6) ? 1.f : 0.f, i7  = (col ==  7) ? 1.f : 0.f;
    const float i8  = (col ==  8) ? 1.f : 0.f, i9  = (col ==  9) ? 1.f : 0.f;
    const float i10 = (col == 10) ? 1.f : 0.f, i11 = (col == 11) ? 1.f : 0.f;
    const float i12 = (col == 12) ? 1.f : 0.f, i13 = (col == 13) ? 1.f : 0.f;
    const float i14 = (col == 14) ? 1.f : 0.f, i15 = (col == 15) ? 1.f : 0.f;

    float w0 = 0.f, w1 = 0.f, w2 = 0.f, w3 = 0.f;

    // prologue: 2-group lead
    float4 X0 = xq[0], X1 = xq[1], X2 = xq[2];
    float4 G0 = gq[0], G1 = gq[1];

    for (int j = 0; j < 26; ++j) {
        const int g = 4 * j;
        float so  = 0.f;
        float gvs = lgs[16 * j + col];             // for the store-time gm

        float4 X3 = xq[g+3];  float4 G2 = gq[g+2];
        GROUP4(X0, X1, G0, i0,  i1,  i2,  i3);

        X0 = xq[g+4];         float4 G3 = gq[g+3];
        GROUP4(X1, X2, G1, i4,  i5,  i6,  i7);

        X1 = xq[g+5];         G0 = gq[g+4];
        GROUP4(X2, X3, G2, i8,  i9,  i10, i11);

        X2 = xq[g+6];         G1 = gq[g+5];
        GROUP4(X3, X0, G3, i12, i13, i14, i15);

        if (j >= 14 || early) {
            float gms = fmaf(-0.05f, so, gvs);     // == in-loop gm bitwise
            od[16 * j + col] = so;                 // d_est
            oe[16 * j + col] = 20.0f * gms;        // e = 20 * (0.05*e)
        }
    }
}

extern "C" void kernel_launch(void* const* d_in, const int* in_sizes, int n_in,
                              void* d_out, int out_size, void* d_ws, size_t ws_size,
                              hipStream_t stream) {
    const float* dmat = (const float*)d_in[0];   // (2, TLEN)
    const float* xvec = (const float*)d_in[1];   // (TLEN,)
    float* out = (float*)d_out;                  // [d_est(2,LROW), e(2,LROW)]

    hipLaunchKernelGGL(lms_kernel, dim3(NFRM / 2), dim3(64), 0, stream,
                       dmat, xvec, out);
}